// Round 3
// baseline (545.068 us; speedup 1.0000x reference)
//
#include <hip/hip_runtime.h>
#include <math.h>

#define N_NODES 100000
#define N_EDGES 1600000
#define HID 48
#define HPAD 64          // padded feature stride: 128 B = one cache line per node
#define ALPHA 0.1f
#define SW 52            // LDS stride (floats) for transposed W: 16B-aligned, gcd(52,32)=4 -> uniform banks

typedef unsigned short u16;
typedef unsigned int u32;

__device__ __forceinline__ float bf_lo(u32 u) { return __uint_as_float(u << 16); }
__device__ __forceinline__ float bf_hi(u32 u) { return __uint_as_float(u & 0xffff0000u); }
__device__ __forceinline__ float bf2f(u16 u) {
    return __uint_as_float(((u32)u) << 16);
}
__device__ __forceinline__ u16 f2bf(float f) {
    u32 b = __float_as_uint(f);
    b += 0x7fff + ((b >> 16) & 1);   // round-to-nearest-even
    return (u16)(b >> 16);
}
__device__ __forceinline__ u32 pack2(float a, float b) {
    return (u32)f2bf(a) | ((u32)f2bf(b) << 16);
}

// ---------------- lin0: h0 = relu(x @ W0 + b0), bf16, padded stride 64 ----------------
// one thread per (node, feature-octet): 8 features -> one uint4 store (16B, line-aligned)
__global__ __launch_bounds__(256) void lin0_k(const float* __restrict__ x, const float* __restrict__ W0,
                                              const float* __restrict__ b0, u16* __restrict__ h0) {
    int t = blockIdx.x * 256 + threadIdx.x;
    if (t >= N_NODES * 6) return;
    int node = t / 6, oct = t % 6;
    float xv0 = x[node * 3 + 0], xv1 = x[node * 3 + 1], xv2 = x[node * 3 + 2];
    float v[8];
#pragma unroll
    for (int j = 0; j < 8; j++) {
        int f = oct * 8 + j;
        float s = b0[f] + xv0 * W0[0 * HID + f] + xv1 * W0[1 * HID + f] + xv2 * W0[2 * HID + f];
        v[j] = s > 0.f ? s : 0.f;
    }
    uint4 p;
    p.x = pack2(v[0], v[1]); p.y = pack2(v[2], v[3]);
    p.z = pack2(v[4], v[5]); p.w = pack2(v[6], v[7]);
    *(uint4*)(h0 + (size_t)node * HPAD + oct * 8) = p;
}

// ---------------- CSR build ----------------
__global__ __launch_bounds__(256) void count_k(const int* __restrict__ dst, int* __restrict__ deg,
                                               int* __restrict__ rank) {
    int e = blockIdx.x * 256 + threadIdx.x;
    if (e < N_EDGES) rank[e] = atomicAdd(&deg[dst[e]], 1);
}

__global__ __launch_bounds__(256) void scan1_k(const int* __restrict__ deg, int* __restrict__ rowptr,
                                               int* __restrict__ partial) {
    __shared__ int sums[256];
    int tid = threadIdx.x;
    int base = blockIdx.x * 2048 + tid * 8;
    int v[8]; int s = 0;
#pragma unroll
    for (int j = 0; j < 8; j++) { int idx = base + j; v[j] = (idx < N_NODES) ? deg[idx] : 0; s += v[j]; }
    sums[tid] = s; __syncthreads();
    for (int off = 1; off < 256; off <<= 1) {
        int t = (tid >= off) ? sums[tid - off] : 0;
        __syncthreads();
        sums[tid] += t;
        __syncthreads();
    }
    if (tid == 255) partial[blockIdx.x] = sums[255];
    int run = (tid > 0) ? sums[tid - 1] : 0;
#pragma unroll
    for (int j = 0; j < 8; j++) { int idx = base + j; if (idx < N_NODES) rowptr[idx] = run; run += v[j]; }
}

// wave-parallel exclusive scan over <=64 block partials
__global__ void scan2_k(int* __restrict__ partial, int* __restrict__ rowptr, int nblk) {
    int lane = threadIdx.x & 63;
    int v = (lane < nblk) ? partial[lane] : 0;
    for (int off = 1; off < 64; off <<= 1) {
        int t = __shfl_up(v, off);
        if (lane >= off) v += t;
    }
    int excl = __shfl_up(v, 1);
    if (lane == 0) excl = 0;
    if (lane < nblk) partial[lane] = excl;
    if (lane == 63) rowptr[N_NODES] = v;
}

__global__ __launch_bounds__(256) void scan3_k(int* __restrict__ rowptr, const int* __restrict__ partial) {
    int tid = threadIdx.x;
    int base = blockIdx.x * 2048 + tid * 8;
    int add = partial[blockIdx.x];
#pragma unroll
    for (int j = 0; j < 8; j++) {
        int idx = base + j;
        if (idx < N_NODES) rowptr[idx] += add;
    }
}

// atomic-free scatter: position = rowptr[dst] + rank
__global__ __launch_bounds__(256) void bucket_k(const int* __restrict__ src, const int* __restrict__ dst,
                                                const int* __restrict__ rank, const int* __restrict__ rowptr,
                                                int* __restrict__ ssrc) {
    int e = blockIdx.x * 256 + threadIdx.x;
    if (e < N_EDGES) {
        int d = dst[e];
        ssrc[rowptr[d] + rank[e]] = src[e];
    }
}

// ---------------- fused layer ----------------
// one wave per node. lane = (slot<<3)|chunk: chunk 0..5 active (feature octet), slot 0..7 (edge).
// h is padded to 64 features (128B line-aligned): every uint4 gather hits exactly ONE cache line.
// 32 edges per loop body: 4 predicated 8-edge groups, all loads issued up front (deg<=32 = one pass).
__global__ __launch_bounds__(256) void layer_k(const u16* __restrict__ h_in, const u16* __restrict__ x0,
                                               const int* __restrict__ rowptr, const int* __restrict__ ssrc,
                                               const float* __restrict__ W, float beta,
                                               u16* __restrict__ h_out) {
    __shared__ float sWT[48 * SW];   // transposed: sWT[c*SW + r] = W[r][c]
    __shared__ float tbuf[4][48];
    int tid = threadIdx.x, wave = tid >> 6, lane = tid & 63;
#pragma unroll
    for (int i = tid; i < 2304; i += 256) {
        int r = i / 48, c = i % 48;
        sWT[c * SW + r] = W[i];
    }
    int node = blockIdx.x * 4 + wave;
    int chunk = lane & 7;           // 0..7 (6 active)
    int slot  = lane >> 3;          // 0..7
    bool act = chunk < 6;
    int cc = act ? chunk : 0;       // idle lanes clamp to octet 0 (same line, no extra fetch)
    float a0 = 0.f, a1 = 0.f, a2 = 0.f, a3 = 0.f, a4 = 0.f, a5 = 0.f, a6 = 0.f, a7 = 0.f;
    if (node < N_NODES) {
        int e0 = rowptr[node], e1 = rowptr[node + 1];
        for (int e = e0; e < e1; e += 32) {
            int i0 = e + slot, i1 = e + 8 + slot, i2 = e + 16 + slot, i3 = e + 24 + slot;
            int s0 = ssrc[i0 < e1 ? i0 : e];
            int s1 = ssrc[i1 < e1 ? i1 : e];
            int s2 = ssrc[i2 < e1 ? i2 : e];
            int s3 = ssrc[i3 < e1 ? i3 : e];
            const uint4 w0 = *(const uint4*)(h_in + ((size_t)s0 << 6) + cc * 8);
            const uint4 w1 = *(const uint4*)(h_in + ((size_t)s1 << 6) + cc * 8);
            const uint4 w2 = *(const uint4*)(h_in + ((size_t)s2 << 6) + cc * 8);
            const uint4 w3 = *(const uint4*)(h_in + ((size_t)s3 << 6) + cc * 8);
            if (i0 < e1) {
                a0 += bf_lo(w0.x); a1 += bf_hi(w0.x); a2 += bf_lo(w0.y); a3 += bf_hi(w0.y);
                a4 += bf_lo(w0.z); a5 += bf_hi(w0.z); a6 += bf_lo(w0.w); a7 += bf_hi(w0.w);
            }
            if (i1 < e1) {
                a0 += bf_lo(w1.x); a1 += bf_hi(w1.x); a2 += bf_lo(w1.y); a3 += bf_hi(w1.y);
                a4 += bf_lo(w1.z); a5 += bf_hi(w1.z); a6 += bf_lo(w1.w); a7 += bf_hi(w1.w);
            }
            if (i2 < e1) {
                a0 += bf_lo(w2.x); a1 += bf_hi(w2.x); a2 += bf_lo(w2.y); a3 += bf_hi(w2.y);
                a4 += bf_lo(w2.z); a5 += bf_hi(w2.z); a6 += bf_lo(w2.w); a7 += bf_hi(w2.w);
            }
            if (i3 < e1) {
                a0 += bf_lo(w3.x); a1 += bf_hi(w3.x); a2 += bf_lo(w3.y); a3 += bf_hi(w3.y);
                a4 += bf_lo(w3.z); a5 += bf_hi(w3.z); a6 += bf_lo(w3.w); a7 += bf_hi(w3.w);
            }
        }
        // rejoin the 8 slot partials (lane bits 3,4,5)
#pragma unroll
        for (int off = 8; off <= 32; off <<= 1) {
            a0 += __shfl_xor(a0, off); a1 += __shfl_xor(a1, off);
            a2 += __shfl_xor(a2, off); a3 += __shfl_xor(a3, off);
            a4 += __shfl_xor(a4, off); a5 += __shfl_xor(a5, off);
            a6 += __shfl_xor(a6, off); a7 += __shfl_xor(a7, off);
        }
        if (act && slot == 0) {
            const uint4 xv = *(const uint4*)(x0 + ((size_t)node << 6) + chunk * 8);
            float4 t0, t1;
            t0.x = (1.f - ALPHA) * a0 + ALPHA * bf_lo(xv.x);
            t0.y = (1.f - ALPHA) * a1 + ALPHA * bf_hi(xv.x);
            t0.z = (1.f - ALPHA) * a2 + ALPHA * bf_lo(xv.y);
            t0.w = (1.f - ALPHA) * a3 + ALPHA * bf_hi(xv.y);
            t1.x = (1.f - ALPHA) * a4 + ALPHA * bf_lo(xv.z);
            t1.y = (1.f - ALPHA) * a5 + ALPHA * bf_hi(xv.z);
            t1.z = (1.f - ALPHA) * a6 + ALPHA * bf_lo(xv.w);
            t1.w = (1.f - ALPHA) * a7 + ALPHA * bf_hi(xv.w);
            ((float4*)tbuf[wave])[chunk * 2 + 0] = t0;
            ((float4*)tbuf[wave])[chunk * 2 + 1] = t1;
        }
    }
    __syncthreads();
    if (node < N_NODES && lane < 48) {
        const float4* t4 = (const float4*)tbuf[wave];
        const float4* w4 = (const float4*)(sWT + lane * SW);
        float s = 0.f;
#pragma unroll
        for (int k4 = 0; k4 < 12; k4++) {
            float4 tv = t4[k4];
            float4 wv = w4[k4];
            s += tv.x * wv.x + tv.y * wv.y + tv.z * wv.z + tv.w * wv.w;
        }
        float t = tbuf[wave][lane];
        float o = (1.f - beta) * t + beta * s;
        h_out[(size_t)node * HPAD + lane] = f2bf(o > 0.f ? o : 0.f);
    }
}

// ---------------- final: out = log_softmax(h @ W1 + b1) ----------------
__global__ __launch_bounds__(256) void final_k(const u16* __restrict__ h, const float* __restrict__ W1,
                                               const float* __restrict__ b1, float* __restrict__ out) {
    __shared__ float sWT[48 * SW];
    __shared__ float sb[48];
    __shared__ float tbuf[4][48];
    int tid = threadIdx.x, wave = tid >> 6, lane = tid & 63;
#pragma unroll
    for (int i = tid; i < 2304; i += 256) {
        int r = i / 48, c = i % 48;
        sWT[c * SW + r] = W1[i];
    }
    if (tid < 48) sb[tid] = b1[tid];
    int node = blockIdx.x * 4 + wave;
    int f = lane < 48 ? lane : 0;
    if (node < N_NODES && lane < 48) tbuf[wave][lane] = bf2f(h[(size_t)node * HPAD + lane]);
    __syncthreads();
    float v = -INFINITY;
    if (node < N_NODES) {
        const float4* t4 = (const float4*)tbuf[wave];
        const float4* w4 = (const float4*)(sWT + f * SW);
        float s = sb[f];
#pragma unroll
        for (int k4 = 0; k4 < 12; k4++) {
            float4 tv = t4[k4];
            float4 wv = w4[k4];
            s += tv.x * wv.x + tv.y * wv.y + tv.z * wv.z + tv.w * wv.w;
        }
        if (lane < 48) v = s;
    }
    float m = v;
    for (int off = 32; off >= 1; off >>= 1) m = fmaxf(m, __shfl_xor(m, off));
    float ex = (node < N_NODES && lane < 48) ? expf(v - m) : 0.f;
    float sum = ex;
    for (int off = 32; off >= 1; off >>= 1) sum += __shfl_xor(sum, off);
    if (node < N_NODES && lane < 48) {
        out[node * 48 + lane] = v - m - logf(sum);
    }
}

extern "C" void kernel_launch(void* const* d_in, const int* in_sizes, int n_in,
                              void* d_out, int out_size, void* d_ws, size_t ws_size,
                              hipStream_t stream) {
    const float* x     = (const float*)d_in[0];
    const int*   ei    = (const int*)d_in[1];
    const float* W0    = (const float*)d_in[2];
    const float* b0    = (const float*)d_in[3];
    const float* convW = (const float*)d_in[4];
    const float* W1    = (const float*)d_in[5];
    const float* b1    = (const float*)d_in[6];
    float* out = (float*)d_out;
    const int* src = ei;            // edge_index[0]
    const int* dst = ei + N_EDGES;  // edge_index[1]

    char* ws = (char*)d_ws;
    size_t off = 0;
    u16* h0 = (u16*)(ws + off); off += (size_t)N_NODES * HPAD * 2;   // 12.8 MB bf16, preserved residual (x0 == h0)
    u16* hA = (u16*)(ws + off); off += (size_t)N_NODES * HPAD * 2;   // 12.8 MB
    u16* hB = (u16*)(ws + off); off += (size_t)N_NODES * HPAD * 2;   // 12.8 MB
    int* rank = (int*)hA;           // alias: rank (6.4 MB) dead after bucket_k; hA first written by layer 2
    int* ssrc = (int*)(ws + off);   off += (size_t)N_EDGES * 4;      // 6.4 MB
    int* rowptr = (int*)(ws + off); off += (size_t)(N_NODES + 1) * 4;
    off = (off + 255) & ~(size_t)255;
    int* deg = (int*)(ws + off);    off += (size_t)N_NODES * 4;
    off = (off + 255) & ~(size_t)255;
    int* partial = (int*)(ws + off); off += 64 * 4;

    hipMemsetAsync(deg, 0, (size_t)N_NODES * 4, stream);

    lin0_k<<<(N_NODES * 6 + 255) / 256, 256, 0, stream>>>(x, W0, b0, h0);
    count_k<<<6250, 256, 0, stream>>>(dst, deg, rank);
    scan1_k<<<49, 256, 0, stream>>>(deg, rowptr, partial);
    scan2_k<<<1, 64, 0, stream>>>(partial, rowptr, 49);
    scan3_k<<<49, 256, 0, stream>>>(rowptr, partial);
    bucket_k<<<6250, 256, 0, stream>>>(src, dst, rank, rowptr, ssrc);

    const float betas[4] = { logf(1.5f), logf(1.25f), logf(7.f / 6.f), logf(1.125f) };

    // x0 residual = h0 (same values); h0 is preserved, hA/hB ping-pong
    layer_k<<<25000, 256, 0, stream>>>(h0, h0, rowptr, ssrc, convW + 0 * 2304, betas[0], hB);
    layer_k<<<25000, 256, 0, stream>>>(hB, h0, rowptr, ssrc, convW + 1 * 2304, betas[1], hA);
    layer_k<<<25000, 256, 0, stream>>>(hA, h0, rowptr, ssrc, convW + 2 * 2304, betas[2], hB);
    layer_k<<<25000, 256, 0, stream>>>(hB, h0, rowptr, ssrc, convW + 3 * 2304, betas[3], hA);
    final_k<<<25000, 256, 0, stream>>>(hA, W1, b1, out);
}

// Round 4
// 511.987 us; speedup vs baseline: 1.0646x; 1.0646x over previous
//
#include <hip/hip_runtime.h>
#include <math.h>

#define N_NODES 100000
#define N_EDGES 1600000
#define HID 48
#define HPAD 64          // padded feature stride: 128 B = one cache line per node
#define ALPHA 0.1f

typedef unsigned short u16;
typedef unsigned int u32;

__device__ __forceinline__ float bf_lo(u32 u) { return __uint_as_float(u << 16); }
__device__ __forceinline__ float bf_hi(u32 u) { return __uint_as_float(u & 0xffff0000u); }
__device__ __forceinline__ float bf2f(u16 u) {
    return __uint_as_float(((u32)u) << 16);
}
__device__ __forceinline__ u16 f2bf(float f) {
    u32 b = __float_as_uint(f);
    b += 0x7fff + ((b >> 16) & 1);   // round-to-nearest-even
    return (u16)(b >> 16);
}
__device__ __forceinline__ u32 pack2(float a, float b) {
    return (u32)f2bf(a) | ((u32)f2bf(b) << 16);
}

// ---------------- lin0: h0 = relu(x @ W0 + b0), bf16, padded stride 64 ----------------
__global__ __launch_bounds__(256) void lin0_k(const float* __restrict__ x, const float* __restrict__ W0,
                                              const float* __restrict__ b0, u16* __restrict__ h0) {
    int t = blockIdx.x * 256 + threadIdx.x;
    if (t >= N_NODES * 6) return;
    int node = t / 6, oct = t % 6;
    float xv0 = x[node * 3 + 0], xv1 = x[node * 3 + 1], xv2 = x[node * 3 + 2];
    float v[8];
#pragma unroll
    for (int j = 0; j < 8; j++) {
        int f = oct * 8 + j;
        float s = b0[f] + xv0 * W0[0 * HID + f] + xv1 * W0[1 * HID + f] + xv2 * W0[2 * HID + f];
        v[j] = s > 0.f ? s : 0.f;
    }
    uint4 p;
    p.x = pack2(v[0], v[1]); p.y = pack2(v[2], v[3]);
    p.z = pack2(v[4], v[5]); p.w = pack2(v[6], v[7]);
    *(uint4*)(h0 + (size_t)node * HPAD + oct * 8) = p;
}

// ---------------- CSR build ----------------
__global__ __launch_bounds__(256) void count_k(const int* __restrict__ dst, int* __restrict__ deg,
                                               int* __restrict__ rank) {
    int e = blockIdx.x * 256 + threadIdx.x;
    if (e < N_EDGES) rank[e] = atomicAdd(&deg[dst[e]], 1);
}

__global__ __launch_bounds__(256) void scan1_k(const int* __restrict__ deg, int* __restrict__ rowptr,
                                               int* __restrict__ partial) {
    __shared__ int sums[256];
    int tid = threadIdx.x;
    int base = blockIdx.x * 2048 + tid * 8;
    int v[8]; int s = 0;
#pragma unroll
    for (int j = 0; j < 8; j++) { int idx = base + j; v[j] = (idx < N_NODES) ? deg[idx] : 0; s += v[j]; }
    sums[tid] = s; __syncthreads();
    for (int off = 1; off < 256; off <<= 1) {
        int t = (tid >= off) ? sums[tid - off] : 0;
        __syncthreads();
        sums[tid] += t;
        __syncthreads();
    }
    if (tid == 255) partial[blockIdx.x] = sums[255];
    int run = (tid > 0) ? sums[tid - 1] : 0;
#pragma unroll
    for (int j = 0; j < 8; j++) { int idx = base + j; if (idx < N_NODES) rowptr[idx] = run; run += v[j]; }
}

// wave-parallel exclusive scan over <=64 block partials
__global__ void scan2_k(int* __restrict__ partial, int* __restrict__ rowptr, int nblk) {
    int lane = threadIdx.x & 63;
    int v = (lane < nblk) ? partial[lane] : 0;
    for (int off = 1; off < 64; off <<= 1) {
        int t = __shfl_up(v, off);
        if (lane >= off) v += t;
    }
    int excl = __shfl_up(v, 1);
    if (lane == 0) excl = 0;
    if (lane < nblk) partial[lane] = excl;
    if (lane == 63) rowptr[N_NODES] = v;
}

__global__ __launch_bounds__(256) void scan3_k(int* __restrict__ rowptr, const int* __restrict__ partial) {
    int tid = threadIdx.x;
    int base = blockIdx.x * 2048 + tid * 8;
    int add = partial[blockIdx.x];
#pragma unroll
    for (int j = 0; j < 8; j++) {
        int idx = base + j;
        if (idx < N_NODES) rowptr[idx] += add;
    }
}

// atomic-free scatter: position = rowptr[dst] + rank
__global__ __launch_bounds__(256) void bucket_k(const int* __restrict__ src, const int* __restrict__ dst,
                                                const int* __restrict__ rank, const int* __restrict__ rowptr,
                                                int* __restrict__ ssrc) {
    int e = blockIdx.x * 256 + threadIdx.x;
    if (e < N_EDGES) {
        int d = dst[e];
        ssrc[rowptr[d] + rank[e]] = src[e];
    }
}

// ---------------- fused layer ----------------
// one wave per node. lane = (slot<<3)|chunk: chunk 0..5 active (feature octet), slot 0..7 (edge).
// h padded to 64 feats (128B): every uint4 gather = exactly one cache line.
// 16-edge main loop (2 gathers in flight) + predicated 8-edge tail: ~right number of
// VMEM ops for Poisson(16) degrees (the always-32 predicated body of R3 wasted 2x).
// W stays ROW-MAJOR in LDS: epilogue reads sW[(4k+j)*48+lane] are lane-stride-1 =
// bank-conflict-free (the R3 transposed ds_read_b128 layout was a 6-way conflict).
__global__ __launch_bounds__(256) void layer_k(const u16* __restrict__ h_in, const u16* __restrict__ x0,
                                               const int* __restrict__ rowptr, const int* __restrict__ ssrc,
                                               const float* __restrict__ W, float beta,
                                               u16* __restrict__ h_out) {
    __shared__ float sW[2304];
    __shared__ float tbuf[4][48];
    int tid = threadIdx.x, wave = tid >> 6, lane = tid & 63;
#pragma unroll
    for (int i = 0; i < 9; i++) sW[i * 256 + tid] = W[i * 256 + tid];
    int node = blockIdx.x * 4 + wave;
    int chunk = lane & 7;           // 0..7 (6 active)
    int slot  = lane >> 3;          // 0..7
    bool act = chunk < 6;
    int cc = act ? chunk : 0;       // idle lanes clamp to octet 0 (same line, no extra fetch)
    float a0 = 0.f, a1 = 0.f, a2 = 0.f, a3 = 0.f, a4 = 0.f, a5 = 0.f, a6 = 0.f, a7 = 0.f;
    if (node < N_NODES) {
        int e0 = rowptr[node], e1 = rowptr[node + 1];
        int e = e0;
        for (; e + 16 <= e1; e += 16) {
            int sA = ssrc[e + slot];
            int sB = ssrc[e + 8 + slot];
            const uint4 wA = *(const uint4*)(h_in + ((size_t)sA << 6) + cc * 8);
            const uint4 wB = *(const uint4*)(h_in + ((size_t)sB << 6) + cc * 8);
            a0 += bf_lo(wA.x) + bf_lo(wB.x);
            a1 += bf_hi(wA.x) + bf_hi(wB.x);
            a2 += bf_lo(wA.y) + bf_lo(wB.y);
            a3 += bf_hi(wA.y) + bf_hi(wB.y);
            a4 += bf_lo(wA.z) + bf_lo(wB.z);
            a5 += bf_hi(wA.z) + bf_hi(wB.z);
            a6 += bf_lo(wA.w) + bf_lo(wB.w);
            a7 += bf_hi(wA.w) + bf_hi(wB.w);
        }
        // predicated 8-edge tail
        for (; e < e1; e += 8) {
            int idx = e + slot;
            int s = ssrc[idx < e1 ? idx : e];   // e < e1 here, ssrc[e] is a safe address
            const uint4 w = *(const uint4*)(h_in + ((size_t)s << 6) + cc * 8);
            if (idx < e1) {
                a0 += bf_lo(w.x); a1 += bf_hi(w.x);
                a2 += bf_lo(w.y); a3 += bf_hi(w.y);
                a4 += bf_lo(w.z); a5 += bf_hi(w.z);
                a6 += bf_lo(w.w); a7 += bf_hi(w.w);
            }
        }
        // rejoin the 8 slot partials (lane bits 3,4,5)
#pragma unroll
        for (int off = 8; off <= 32; off <<= 1) {
            a0 += __shfl_xor(a0, off); a1 += __shfl_xor(a1, off);
            a2 += __shfl_xor(a2, off); a3 += __shfl_xor(a3, off);
            a4 += __shfl_xor(a4, off); a5 += __shfl_xor(a5, off);
            a6 += __shfl_xor(a6, off); a7 += __shfl_xor(a7, off);
        }
        if (act && slot == 0) {
            const uint4 xv = *(const uint4*)(x0 + ((size_t)node << 6) + chunk * 8);
            float4 t0, t1;
            t0.x = (1.f - ALPHA) * a0 + ALPHA * bf_lo(xv.x);
            t0.y = (1.f - ALPHA) * a1 + ALPHA * bf_hi(xv.x);
            t0.z = (1.f - ALPHA) * a2 + ALPHA * bf_lo(xv.y);
            t0.w = (1.f - ALPHA) * a3 + ALPHA * bf_hi(xv.y);
            t1.x = (1.f - ALPHA) * a4 + ALPHA * bf_lo(xv.z);
            t1.y = (1.f - ALPHA) * a5 + ALPHA * bf_hi(xv.z);
            t1.z = (1.f - ALPHA) * a6 + ALPHA * bf_lo(xv.w);
            t1.w = (1.f - ALPHA) * a7 + ALPHA * bf_hi(xv.w);
            ((float4*)tbuf[wave])[chunk * 2 + 0] = t0;
            ((float4*)tbuf[wave])[chunk * 2 + 1] = t1;
        }
    }
    __syncthreads();
    if (node < N_NODES && lane < 48) {
        const float4* t4 = (const float4*)tbuf[wave];
        float s = 0.f;
#pragma unroll
        for (int k4 = 0; k4 < 12; k4++) {
            float4 tv = t4[k4];
            s += tv.x * sW[(4 * k4 + 0) * 48 + lane] + tv.y * sW[(4 * k4 + 1) * 48 + lane]
               + tv.z * sW[(4 * k4 + 2) * 48 + lane] + tv.w * sW[(4 * k4 + 3) * 48 + lane];
        }
        float t = tbuf[wave][lane];
        float o = (1.f - beta) * t + beta * s;
        h_out[(size_t)node * HPAD + lane] = f2bf(o > 0.f ? o : 0.f);
    }
}

// ---------------- final: out = log_softmax(h @ W1 + b1) ----------------
__global__ __launch_bounds__(256) void final_k(const u16* __restrict__ h, const float* __restrict__ W1,
                                               const float* __restrict__ b1, float* __restrict__ out) {
    __shared__ float sW[2304];
    __shared__ float sb[48];
    __shared__ float tbuf[4][48];
    int tid = threadIdx.x, wave = tid >> 6, lane = tid & 63;
#pragma unroll
    for (int i = 0; i < 9; i++) sW[i * 256 + tid] = W1[i * 256 + tid];
    if (tid < 48) sb[tid] = b1[tid];
    int node = blockIdx.x * 4 + wave;
    int f = lane < 48 ? lane : 0;
    if (node < N_NODES && lane < 48) tbuf[wave][lane] = bf2f(h[(size_t)node * HPAD + lane]);
    __syncthreads();
    float v = -INFINITY;
    if (node < N_NODES) {
        const float4* t4 = (const float4*)tbuf[wave];
        float s = sb[f];
#pragma unroll
        for (int k4 = 0; k4 < 12; k4++) {
            float4 tv = t4[k4];
            s += tv.x * sW[(4 * k4 + 0) * 48 + f] + tv.y * sW[(4 * k4 + 1) * 48 + f]
               + tv.z * sW[(4 * k4 + 2) * 48 + f] + tv.w * sW[(4 * k4 + 3) * 48 + f];
        }
        if (lane < 48) v = s;
    }
    float m = v;
    for (int off = 32; off >= 1; off >>= 1) m = fmaxf(m, __shfl_xor(m, off));
    float ex = (node < N_NODES && lane < 48) ? expf(v - m) : 0.f;
    float sum = ex;
    for (int off = 32; off >= 1; off >>= 1) sum += __shfl_xor(sum, off);
    if (node < N_NODES && lane < 48) {
        out[node * 48 + lane] = v - m - logf(sum);
    }
}

extern "C" void kernel_launch(void* const* d_in, const int* in_sizes, int n_in,
                              void* d_out, int out_size, void* d_ws, size_t ws_size,
                              hipStream_t stream) {
    const float* x     = (const float*)d_in[0];
    const int*   ei    = (const int*)d_in[1];
    const float* W0    = (const float*)d_in[2];
    const float* b0    = (const float*)d_in[3];
    const float* convW = (const float*)d_in[4];
    const float* W1    = (const float*)d_in[5];
    const float* b1    = (const float*)d_in[6];
    float* out = (float*)d_out;
    const int* src = ei;            // edge_index[0]
    const int* dst = ei + N_EDGES;  // edge_index[1]

    char* ws = (char*)d_ws;
    size_t off = 0;
    u16* h0 = (u16*)(ws + off); off += (size_t)N_NODES * HPAD * 2;   // 12.8 MB bf16, preserved residual (x0 == h0)
    u16* hA = (u16*)(ws + off); off += (size_t)N_NODES * HPAD * 2;   // 12.8 MB
    u16* hB = (u16*)(ws + off); off += (size_t)N_NODES * HPAD * 2;   // 12.8 MB
    int* rank = (int*)hA;           // alias: rank (6.4 MB) dead after bucket_k; hA first written by layer 2
    int* ssrc = (int*)(ws + off);   off += (size_t)N_EDGES * 4;      // 6.4 MB
    int* rowptr = (int*)(ws + off); off += (size_t)(N_NODES + 1) * 4;
    off = (off + 255) & ~(size_t)255;
    int* deg = (int*)(ws + off);    off += (size_t)N_NODES * 4;
    off = (off + 255) & ~(size_t)255;
    int* partial = (int*)(ws + off); off += 64 * 4;

    hipMemsetAsync(deg, 0, (size_t)N_NODES * 4, stream);

    lin0_k<<<(N_NODES * 6 + 255) / 256, 256, 0, stream>>>(x, W0, b0, h0);
    count_k<<<6250, 256, 0, stream>>>(dst, deg, rank);
    scan1_k<<<49, 256, 0, stream>>>(deg, rowptr, partial);
    scan2_k<<<1, 64, 0, stream>>>(partial, rowptr, 49);
    scan3_k<<<49, 256, 0, stream>>>(rowptr, partial);
    bucket_k<<<6250, 256, 0, stream>>>(src, dst, rank, rowptr, ssrc);

    const float betas[4] = { logf(1.5f), logf(1.25f), logf(7.f / 6.f), logf(1.125f) };

    // x0 residual = h0 (same values); h0 preserved, hA/hB ping-pong
    layer_k<<<25000, 256, 0, stream>>>(h0, h0, rowptr, ssrc, convW + 0 * 2304, betas[0], hB);
    layer_k<<<25000, 256, 0, stream>>>(hB, h0, rowptr, ssrc, convW + 1 * 2304, betas[1], hA);
    layer_k<<<25000, 256, 0, stream>>>(hA, h0, rowptr, ssrc, convW + 2 * 2304, betas[2], hB);
    layer_k<<<25000, 256, 0, stream>>>(hB, h0, rowptr, ssrc, convW + 3 * 2304, betas[3], hA);
    final_k<<<25000, 256, 0, stream>>>(hA, W1, b1, out);
}